// Round 10
// baseline (3314.312 us; speedup 1.0000x reference)
//
#include <hip/hip_runtime.h>
#include <hip/hip_cooperative_groups.h>

namespace cg = cooperative_groups;

// 400-step diffusion stencil; PERSISTENT cooperative kernel: 1 launch,
// 25 supersteps x 16 substeps, grid.sync() between supersteps.
// u_{t+1} = mask * (u_t + 0.225 * lap5(u_t) + dt * a), zero Dirichlet mask.
//
// Round-10 change (rounds 7-9 all ~780us: substep-loop tweaks neutral ->
// fixed per-launch cost ~23us dominates: a-restage 16.8MB + u-restage
// 16.8MB + prologue VALU + launch overhead, x25):
//  - fr/mk staged ONCE for the whole run (a never changes).
//  - u stays in registers across supersteps; after each superstep write the
//    96x96 core, threadfence+grid.sync, reload ONLY the 16-wide halo ring
//    (7.3MB instead of 16.8MB full tile).
//  - ping-pong dst: even supersteps -> out (sup 24 = final -> out), odd ->
//    ws. One sync/superstep is race-free: the next write of a buffer is
//    separated from all reads of it by the following grid.sync.
// Per-superstep structure otherwise identical to round 9 (validated):
// register strips 8x4, LDS halo rows double-buffered, DPP lane shifts,
// ring>=s invariant makes core rows/cols 16..111 exact per superstep.

#define HH 1501
#define NSUP 25
#define TSTEPS 16
#define BB 96
#define IN 128           // BB + 2*TSTEPS
#define NTH 512          // 32 col-quads x 16 row-groups (8 rows each)
#define DT 1e-7f
#define SP 0.225f

__device__ __forceinline__ float dpp_shr1(float x) {   // lane n <- lane n-1
    return __int_as_float(__builtin_amdgcn_update_dpp(
        0, __float_as_int(x), 0x138, 0xF, 0xF, true));
}
__device__ __forceinline__ float dpp_shl1(float x) {   // lane n <- lane n+1
    return __int_as_float(__builtin_amdgcn_update_dpp(
        0, __float_as_int(x), 0x130, 0xF, 0xF, true));
}

__global__ __launch_bounds__(NTH, 1) void furnace_persist(
    const float* __restrict__ u0,
    const float* __restrict__ a,
    float* __restrict__ out,
    float* __restrict__ ws)
{
    // halo rows, double-buffered, all ds_*_b128 conflict-free.
    __shared__ __align__(16) float h_top[2][17][IN];
    __shared__ __align__(16) float h_bot[2][17][IN];

    cg::grid_group gg = cg::this_grid();

    const int tid = threadIdx.x;
    const int cq  = tid & 31;        // column quad (cols 4cq..4cq+3)
    const int gs  = tid >> 5;        // row group 0..15 (rows 8gs..8gs+7)
    const int ox  = blockIdx.x * BB;
    const int oy  = blockIdx.y * BB;
    const int c0  = 4 * cq;
    const int gx0 = ox - TSTEPS + c0;
    const int rbeg = 8 * gs;         // 0,8,...,120

    float4 u[8], fr[8], mk[8];

    // ---- stage u strip + forcing + mask into registers (ONCE) ----
    #pragma unroll
    for (int j = 0; j < 8; ++j) {
        const int rr = rbeg + j;
        const int gy = oy - TSTEPS + rr;
        const bool rowin = (gy >= 0 && gy < HH);
        const float rowm = (gy <= 0 || gy >= HH - 1) ? 0.0f : 1.0f;
        float tu[4], tf[4], tm[4];
        #pragma unroll
        for (int k = 0; k < 4; ++k) {
            const int gx = gx0 + k;
            const bool inb = rowin && (gx >= 0 && gx < HH);
            tu[k] = inb ? u0[gy * HH + gx] : 0.0f;
            tf[k] = inb ? DT * a[gy * HH + gx] : 0.0f;
            tm[k] = (gx <= 0 || gx >= HH - 1) ? 0.0f : rowm;
        }
        u[j]  = make_float4(tu[0], tu[1], tu[2], tu[3]);
        fr[j] = make_float4(tf[0], tf[1], tf[2], tf[3]);
        mk[j] = make_float4(tm[0], tm[1], tm[2], tm[3]);
    }

    // zero the never-written halo slots (deterministic ring-0 garbage)
    if (gs == 0) {
        const float4 z = make_float4(0.f, 0.f, 0.f, 0.f);
        *(float4*)&h_bot[0][0][c0]  = z;
        *(float4*)&h_bot[1][0][c0]  = z;
        *(float4*)&h_top[0][16][c0] = z;
        *(float4*)&h_top[1][16][c0] = z;
    }

    const bool coreTh  = (cq >= 4 && cq <= 27 && gs >= 2 && gs <= 13);
    const bool colHalo = (cq < 4) || (cq >= 28);

    #pragma unroll 1
    for (int sup = 0; sup < NSUP; ++sup) {
        // ---- 16 substeps, one block-barrier each ----
        #pragma unroll 1
        for (int s = 0; s < TSTEPS; ++s) {
            const int b = s & 1;
            *(float4*)&h_top[b][gs][c0]     = u[0];   // my top row (old)
            *(float4*)&h_bot[b][gs + 1][c0] = u[7];   // my bottom row (old)
            __syncthreads();
            float4 pold = *(const float4*)&h_bot[b][gs][c0];      // rbeg-1
            const float4 dne = *(const float4*)&h_top[b][gs + 1][c0]; // rbeg+8
            #pragma unroll
            for (int j = 0; j < 8; ++j) {
                const float4 cur = u[j];
                const float4 dnv = (j < 7) ? u[j + 1] : dne;
                const float lf = dpp_shr1(cur.w);    // col c0-1 (old)
                const float rt = dpp_shl1(cur.x);    // col c0+4 (old)
                float4 nv;
                nv.x = (cur.x + SP * ((lf    + cur.y) + (pold.x + dnv.x) - 4.0f * cur.x) + fr[j].x) * mk[j].x;
                nv.y = (cur.y + SP * ((cur.x + cur.z) + (pold.y + dnv.y) - 4.0f * cur.y) + fr[j].y) * mk[j].y;
                nv.z = (cur.z + SP * ((cur.y + cur.w) + (pold.z + dnv.z) - 4.0f * cur.z) + fr[j].z) * mk[j].z;
                nv.w = (cur.w + SP * ((cur.z + rt   ) + (pold.w + dnv.w) - 4.0f * cur.w) + fr[j].w) * mk[j].w;
                u[j] = nv;
                pold = cur;
            }
        }

        // ---- write 96x96 core (tile rows/cols 16..111) ----
        float* dst = (sup & 1) ? ws : out;   // sup 24 (even) -> out
        if (coreTh) {
            #pragma unroll
            for (int j = 0; j < 8; ++j) {
                const int rr = rbeg + j;              // 16..111
                const int gy = oy + (rr - TSTEPS);
                if (gy < HH) {
                    const float v[4] = { u[j].x, u[j].y, u[j].z, u[j].w };
                    #pragma unroll
                    for (int k = 0; k < 4; ++k) {
                        const int gx = gx0 + k;
                        if (gx < HH) dst[gy * HH + gx] = v[k];
                    }
                }
            }
        }

        __threadfence();       // device-scope visibility across XCDs
        gg.sync();

        // ---- reload the 16-wide halo ring from dst (written this sup) ----
        if (sup < NSUP - 1 && !coreTh) {
            #pragma unroll
            for (int j = 0; j < 8; ++j) {
                const int rr = rbeg + j;
                const bool rowHalo = (rr < TSTEPS) || (rr >= TSTEPS + BB);
                if (rowHalo || colHalo) {
                    const int gy = oy - TSTEPS + rr;
                    const bool rowin = (gy >= 0 && gy < HH);
                    float t[4];
                    #pragma unroll
                    for (int k = 0; k < 4; ++k) {
                        const int gx = gx0 + k;
                        t[k] = (rowin && gx >= 0 && gx < HH)
                             ? dst[gy * HH + gx] : 0.0f;
                    }
                    u[j] = make_float4(t[0], t[1], t[2], t[3]);
                }
            }
        }
        // next write of this buffer is 2 supersteps away, separated from all
        // reads by the next gg.sync() -> race-free with 1 sync/superstep.
    }
}

extern "C" void kernel_launch(void* const* d_in, const int* in_sizes, int n_in,
                              void* d_out, int out_size, void* d_ws, size_t ws_size,
                              hipStream_t stream)
{
    const float* u0 = (const float*)d_in[0];
    const float* a  = (const float*)d_in[1];
    float* out = (float*)d_out;
    float* ws  = (float*)d_ws;   // one H*H fp32 buffer (9.01 MB)

    dim3 block(NTH, 1, 1);
    dim3 grid((HH + BB - 1) / BB, (HH + BB - 1) / BB, 1);  // 16 x 16 = 256

    void* kargs[] = { (void*)&u0, (void*)&a, (void*)&out, (void*)&ws };
    hipLaunchCooperativeKernel((const void*)furnace_persist, grid, block,
                               kargs, 0, stream);
}

// Round 11
// 897.870 us; speedup vs baseline: 3.6913x; 3.6913x over previous
//
#include <hip/hip_runtime.h>

// 400-step diffusion stencil; temporal blocking, 16 steps/launch, 25 launches.
// u_{t+1} = mask * (u_t + 0.225 * lap5(u_t) + dt * a), zero Dirichlet mask.
//
// Round-11 (revert round-10 cooperative: grid.sync+fence on non-coherent
// per-XCD L2 cost ~100us/superstep, 4.2x regression). Base = round 9
// (786 us). Single theme: COALESCED global access via one LDS stage tile.
//  - u staged lane-contiguous (grid-stride dword) -> LDS -> ds_read_b128
//    into registers (was: per-thread stride-4 scalar loads, 4x transactions).
//  - a staged the same way through the SAME tile -> fr registers.
//  - writeout: core rows ds_write_b128 -> LDS -> grid-stride coalesced
//    stores (was stride-4 scalar stores).
// Substep loop unchanged from round 9 (register strips 8x4, halo rows in
// LDS double-buffered, DPP lane shifts, 1 barrier/substep).
// Validity: ring>=s invariant; core rows/cols 16..111 exact (5 rounds).
// LDS: stage 64KB + halos 34.8KB = 98.8KB -> 1 block/CU (by design).

#define HH 1501
#define NUM_T 400
#define TSTEPS 16
#define BB 96
#define IN 128           // BB + 2*TSTEPS; power of 2 -> cheap r,c split
#define NTH 512          // 32 col-quads x 16 row-groups (8 rows each)
#define DT 1e-7f
#define SP 0.225f

__device__ __forceinline__ float dpp_shr1(float x) {   // lane n <- lane n-1
    return __int_as_float(__builtin_amdgcn_update_dpp(
        0, __float_as_int(x), 0x138, 0xF, 0xF, true));
}
__device__ __forceinline__ float dpp_shl1(float x) {   // lane n <- lane n+1
    return __int_as_float(__builtin_amdgcn_update_dpp(
        0, __float_as_int(x), 0x130, 0xF, 0xF, true));
}

__global__ __launch_bounds__(NTH) void furnace_tb(
    const float* __restrict__ uin,
    const float* __restrict__ a,
    float* __restrict__ uout)
{
    __shared__ __align__(16) float stage[IN * IN];        // 64 KB
    __shared__ __align__(16) float h_top[2][17][IN];      // halo rows,
    __shared__ __align__(16) float h_bot[2][17][IN];      // double-buffered

    const int tid = threadIdx.x;
    const int cq  = tid & 31;        // column quad (cols 4cq..4cq+3)
    const int gs  = tid >> 5;        // row group 0..15 (rows 8gs..8gs+7)
    const int ox  = blockIdx.x * BB;
    const int oy  = blockIdx.y * BB;
    const int c0  = 4 * cq;
    const int gx0 = ox - TSTEPS + c0;
    const int rbeg = 8 * gs;         // 0,8,...,120

    // ---- stage u-tile, lane-contiguous (coalesced) ----
    for (int i = tid; i < IN * IN; i += NTH) {
        const int r = i >> 7, c = i & (IN - 1);
        const int gy = oy - TSTEPS + r;
        const int gx = ox - TSTEPS + c;
        const bool inb = (gx >= 0 && gx < HH && gy >= 0 && gy < HH);
        stage[i] = inb ? uin[gy * HH + gx] : 0.0f;
    }
    __syncthreads();

    float4 u[8], fr[8], mk[8];

    // ---- registers from LDS (b128, contiguous per half-wave) ----
    #pragma unroll
    for (int j = 0; j < 8; ++j)
        u[j] = *(const float4*)&stage[(rbeg + j) * IN + c0];
    __syncthreads();   // all reads done before tile reuse

    // ---- stage a-tile through the same LDS, then fr registers ----
    for (int i = tid; i < IN * IN; i += NTH) {
        const int r = i >> 7, c = i & (IN - 1);
        const int gy = oy - TSTEPS + r;
        const int gx = ox - TSTEPS + c;
        const bool inb = (gx >= 0 && gx < HH && gy >= 0 && gy < HH);
        stage[i] = inb ? a[gy * HH + gx] : 0.0f;
    }
    __syncthreads();
    #pragma unroll
    for (int j = 0; j < 8; ++j) {
        const float4 av = *(const float4*)&stage[(rbeg + j) * IN + c0];
        fr[j] = make_float4(DT * av.x, DT * av.y, DT * av.z, DT * av.w);
        const int gy = oy - TSTEPS + rbeg + j;
        const float rowm = (gy <= 0 || gy >= HH - 1) ? 0.0f : 1.0f;
        float tm[4];
        #pragma unroll
        for (int k = 0; k < 4; ++k) {
            const int gx = gx0 + k;
            tm[k] = (gx <= 0 || gx >= HH - 1) ? 0.0f : rowm;
        }
        mk[j] = make_float4(tm[0], tm[1], tm[2], tm[3]);
    }

    // zero the never-written halo slots (deterministic ring-0 garbage)
    if (gs == 0) {
        const float4 z = make_float4(0.f, 0.f, 0.f, 0.f);
        *(float4*)&h_bot[0][0][c0]  = z;
        *(float4*)&h_bot[1][0][c0]  = z;
        *(float4*)&h_top[0][16][c0] = z;
        *(float4*)&h_top[1][16][c0] = z;
    }

    // ---- 16 substeps, one barrier each (round-9 structure, validated) ----
    #pragma unroll 1
    for (int s = 0; s < TSTEPS; ++s) {
        const int b = s & 1;
        *(float4*)&h_top[b][gs][c0]     = u[0];   // my top row (old)
        *(float4*)&h_bot[b][gs + 1][c0] = u[7];   // my bottom row (old)
        __syncthreads();
        float4 pold = *(const float4*)&h_bot[b][gs][c0];      // row rbeg-1
        const float4 dne = *(const float4*)&h_top[b][gs + 1][c0]; // rbeg+8
        #pragma unroll
        for (int j = 0; j < 8; ++j) {
            const float4 cur = u[j];
            const float4 dnv = (j < 7) ? u[j + 1] : dne;
            const float lf = dpp_shr1(cur.w);    // col c0-1 (old)
            const float rt = dpp_shl1(cur.x);    // col c0+4 (old)
            float4 nv;
            nv.x = (cur.x + SP * ((lf    + cur.y) + (pold.x + dnv.x) - 4.0f * cur.x) + fr[j].x) * mk[j].x;
            nv.y = (cur.y + SP * ((cur.x + cur.z) + (pold.y + dnv.y) - 4.0f * cur.y) + fr[j].y) * mk[j].y;
            nv.z = (cur.z + SP * ((cur.y + cur.w) + (pold.z + dnv.z) - 4.0f * cur.z) + fr[j].z) * mk[j].z;
            nv.w = (cur.w + SP * ((cur.z + rt   ) + (pold.w + dnv.w) - 4.0f * cur.w) + fr[j].w) * mk[j].w;
            u[j] = nv;
            pold = cur;
        }
        // next substep writes the OTHER buffer; barrier above orders reuse.
    }

    // ---- writeout via LDS: core regs -> stage -> coalesced stores ----
    __syncthreads();   // staging tile free (a-reads long done); order w/ loop
    if (cq >= 4 && cq <= 27 && gs >= 2 && gs <= 13) {
        #pragma unroll
        for (int j = 0; j < 8; ++j)
            *(float4*)&stage[(rbeg + j) * IN + c0] = u[j];
    }
    __syncthreads();
    for (int i = tid; i < BB * BB; i += NTH) {
        const int r = i / BB, c = i - r * BB;     // div by 96 -> magic mul
        const int gy = oy + r, gx = ox + c;
        if (gy < HH && gx < HH)
            uout[gy * HH + gx] = stage[(r + TSTEPS) * IN + (c + TSTEPS)];
    }
}

extern "C" void kernel_launch(void* const* d_in, const int* in_sizes, int n_in,
                              void* d_out, int out_size, void* d_ws, size_t ws_size,
                              hipStream_t stream)
{
    const float* u0 = (const float*)d_in[0];
    const float* a  = (const float*)d_in[1];
    float* out = (float*)d_out;
    float* ws  = (float*)d_ws;   // one H*H fp32 buffer (9.01 MB)

    dim3 block(NTH, 1, 1);
    dim3 grid((HH + BB - 1) / BB, (HH + BB - 1) / BB, 1);  // 16 x 16 = 256

    const int nLaunch = NUM_T / TSTEPS;  // 25
    const float* src = u0;
    for (int k = 0; k < nLaunch; ++k) {
        float* dst = (k & 1) ? ws : out;   // k even -> d_out; k=24 -> d_out
        furnace_tb<<<grid, block, 0, stream>>>(src, a, dst);
        src = dst;
    }
}